// Round 13
// baseline (409.694 us; speedup 1.0000x reference)
//
#include <hip/hip_runtime.h>

#define Bsz 64
#define Lsz 4096
#define Dsz 512
#define Hsz 512
#define Usz 256
#define LT  32
#define TPB 16                  // tiles per persistent block
#define NQB 8                   // blocks per batch -> 512 blocks

typedef __attribute__((ext_vector_type(8))) short s8v;     // bf16x8 MFMA frag
typedef __attribute__((ext_vector_type(4))) float f4v;
typedef __attribute__((ext_vector_type(8))) unsigned short u16x8;

// XOR swizzle: 16B slot ^= row&7 (bijective, b128-aligned), c in shorts
#define SW(r, c) (((((c) >> 3) ^ ((r) & 7)) << 3) | ((c) & 7))

__device__ __forceinline__ unsigned short f2bf(float f) {
    unsigned int u = __float_as_uint(f);
    u += 0x7FFFu + ((u >> 16) & 1u);   // RNE
    return (unsigned short)(u >> 16);
}
__device__ __forceinline__ float bf2f(unsigned int lo16) {
    return __uint_as_float(lo16 << 16);
}
__device__ __forceinline__ void barrier_lds() {
    asm volatile("s_waitcnt lgkmcnt(0)" ::: "memory");
    __builtin_amdgcn_s_barrier();
}

// ws layout
//   [0,     256K)      : W1T bf16 [256][512]
//   [256K,  512K)      : hp_part f32 [4][64][256]
//   [512K, 1536K)      : el_arr f32 [64][4096]
//   [1536K, +256B)     : den f32 [64]
//   [1536K+256, +128K) : ctx_acc f32 [64][512]

__global__ __launch_bounds__(256) void k_prep(const float* __restrict__ W1,
                                              const float* __restrict__ hidden,
                                              const float* __restrict__ W2,
                                              unsigned short* __restrict__ W1T,
                                              float* __restrict__ hp_part,
                                              float* __restrict__ den,
                                              float* __restrict__ ctx_acc) {
    int blk = blockIdx.x, tid = threadIdx.x;
    if (blk < 32) {
        __shared__ unsigned short Lt[64][72];
        int kb = blk >> 2, ub = blk & 3;
        {
            int rr = tid >> 2, c16 = (tid & 3) * 16;
            const float* src = W1 + (size_t)(kb * 64 + rr) * Usz + ub * 64 + c16;
            f4v v0 = *reinterpret_cast<const f4v*>(src);
            f4v v1 = *reinterpret_cast<const f4v*>(src + 4);
            f4v v2 = *reinterpret_cast<const f4v*>(src + 8);
            f4v v3 = *reinterpret_cast<const f4v*>(src + 12);
            u16x8 o0 = { f2bf(v0.x), f2bf(v0.y), f2bf(v0.z), f2bf(v0.w),
                         f2bf(v1.x), f2bf(v1.y), f2bf(v1.z), f2bf(v1.w) };
            u16x8 o1 = { f2bf(v2.x), f2bf(v2.y), f2bf(v2.z), f2bf(v2.w),
                         f2bf(v3.x), f2bf(v3.y), f2bf(v3.z), f2bf(v3.w) };
            *reinterpret_cast<u16x8*>(&Lt[rr][c16])     = o0;
            *reinterpret_cast<u16x8*>(&Lt[rr][c16 + 8]) = o1;
        }
        __syncthreads();
        {
            int ur = tid >> 2, k16 = (tid & 3) * 16;
            u16x8 o0, o1;
#pragma unroll
            for (int i = 0; i < 8; ++i) o0[i] = Lt[k16 + i][ur];
#pragma unroll
            for (int i = 0; i < 8; ++i) o1[i] = Lt[k16 + 8 + i][ur];
            unsigned short* dst = W1T + (size_t)(ub * 64 + ur) * Dsz + kb * 64 + k16;
            *reinterpret_cast<u16x8*>(dst)     = o0;
            *reinterpret_cast<u16x8*>(dst + 8) = o1;
        }
    } else if (blk < 288) {
        int idx = blk - 32;
        int kq = idx >> 6, b = idx & 63;
        const float* hrow = hidden + (size_t)b * Hsz + kq * 128;
        const float* w2p  = W2 + (size_t)(kq * 128) * Usz + tid;
        float a0 = 0.f, a1 = 0.f, a2 = 0.f, a3 = 0.f;
#pragma unroll 8
        for (int k = 0; k < 128; k += 4) {
            a0 = fmaf(hrow[k + 0], w2p[(size_t)(k + 0) * Usz], a0);
            a1 = fmaf(hrow[k + 1], w2p[(size_t)(k + 1) * Usz], a1);
            a2 = fmaf(hrow[k + 2], w2p[(size_t)(k + 2) * Usz], a2);
            a3 = fmaf(hrow[k + 3], w2p[(size_t)(k + 3) * Usz], a3);
        }
        hp_part[((size_t)kq * Bsz + b) * Usz + tid] = (a0 + a1) + (a2 + a3);
    } else {
        int b = blk - 288;
        if (tid == 0) den[b] = 0.f;
        ctx_acc[b * Dsz + tid] = 0.f;
        ctx_acc[b * Dsz + 256 + tid] = 0.f;
    }
}

#define LOADB(dst, g)                                                          \
    {                                                                          \
        dst[0] = *reinterpret_cast<const s8v*>(bp0 + (2 * (g)) * 32);          \
        dst[1] = *reinterpret_cast<const s8v*>(bp1 + (2 * (g)) * 32);          \
        dst[2] = *reinterpret_cast<const s8v*>(bp0 + (2 * (g) + 1) * 32);      \
        dst[3] = *reinterpret_cast<const s8v*>(bp1 + (2 * (g) + 1) * 32);      \
    }

#define GEMM2(ks, c0, c1)                                                      \
    {                                                                          \
        const int kof = (ks) * 32 + lg * 8;                                    \
        s8v a0 = *reinterpret_cast<const s8v*>(&A[lr][SW(lr, kof)]);           \
        s8v a1 = *reinterpret_cast<const s8v*>(&A[16 + lr][SW(16 + lr, kof)]); \
        acc00 = __builtin_amdgcn_mfma_f32_16x16x32_bf16(a0, c0, acc00, 0, 0, 0); \
        acc01 = __builtin_amdgcn_mfma_f32_16x16x32_bf16(a0, c1, acc01, 0, 0, 0); \
        acc10 = __builtin_amdgcn_mfma_f32_16x16x32_bf16(a1, c0, acc10, 0, 0, 0); \
        acc11 = __builtin_amdgcn_mfma_f32_16x16x32_bf16(a1, c1, acc11, 0, 0, 0); \
    }

#define GROUP(g, cur, nxt)                                                     \
    {                                                                          \
        if ((g) < 7) LOADB(nxt, (g) + 1);                                      \
        __builtin_amdgcn_sched_barrier(0);                                     \
        GEMM2(2 * (g),     cur[0], cur[1]);                                    \
        GEMM2(2 * (g) + 1, cur[2], cur[3]);                                    \
    }

// Persistent: 512 blocks x 512 thr (8 waves, 2 blocks/CU @128 VGPR).
// Block (b,q8) owns 16 consecutive 32-row tiles. Next tile's features are
// issued at tile start and stay in flight through GEMM+epilogue+score+ctx
// (~5000cy >> 900cy HBM latency) -> HBM loads outstanding ~continuously.
__global__ void __launch_bounds__(512)
__attribute__((amdgpu_waves_per_eu(4, 4))) k_score_ctx(
    const float* __restrict__ feat, const unsigned short* __restrict__ W1T,
    const float* __restrict__ hp_part, const float* __restrict__ W1b,
    const float* __restrict__ W2b, const float* __restrict__ Vk,
    const float* __restrict__ Vb, float* __restrict__ el_arr,
    float* __restrict__ den, float* __restrict__ ctx_acc)
{
    __shared__ __align__(16) unsigned short A[LT][Dsz];  // 32 KiB, swizzled
    __shared__ float hp[Usz], vv[Usz];
    __shared__ float spart[8][LT];
    __shared__ float el[LT];
    __shared__ float pc[2][Dsz];

    const int tid  = threadIdx.x;
    const int w    = tid >> 6;
    const int lane = tid & 63;
    const int lr   = lane & 15;
    const int lg   = lane >> 4;
    const int b    = blockIdx.x >> 3;
    const int q8   = blockIdx.x & 7;

    if (tid < Usz) {
        const float* hpb = hp_part + (size_t)b * Usz + tid;
        hp[tid] = (hpb[0] + hpb[Bsz * Usz]) + (hpb[2 * Bsz * Usz] + hpb[3 * Bsz * Usz])
                + W1b[tid] + W2b[tid];
        vv[tid] = Vk[tid];
    }

    const int srow = tid >> 4;            // 0..31
    const int sfc  = (tid & 15) * 32;     // thread owns 32 consecutive floats
    const float* fb = feat + ((size_t)b * Lsz + q8 * (TPB * LT) + srow) * Dsz + sfc;

    // ---- prologue: stage tile 0 ----
    f4v st[8];
#pragma unroll
    for (int i = 0; i < 8; ++i) st[i] = *reinterpret_cast<const f4v*>(fb + i * 4);
    {
#pragma unroll
        for (int j = 0; j < 4; ++j) {
            u16x8 o = { f2bf(st[2 * j].x),     f2bf(st[2 * j].y),
                        f2bf(st[2 * j].z),     f2bf(st[2 * j].w),
                        f2bf(st[2 * j + 1].x), f2bf(st[2 * j + 1].y),
                        f2bf(st[2 * j + 1].z), f2bf(st[2 * j + 1].w) };
            *reinterpret_cast<u16x8*>(&A[srow][SW(srow, sfc + j * 8)]) = o;
        }
    }
    barrier_lds();

    const unsigned short* bp0 = W1T + (size_t)(w * 32 + lr) * Dsz + lg * 8;
    const unsigned short* bp1 = bp0 + 16 * Dsz;

    float cacc0 = 0.f, cacc1 = 0.f;       // persistent ctx accumulators
    float dsum  = 0.f;                    // persistent denominator (lanes tid<LT)
    const int half = tid >> 8;            // 0..1
    const int d0   = (tid & 255) * 2;

#pragma unroll 1
    for (int t = 0; t < TPB; ++t) {
        f4v acc00 = (f4v){0.f, 0.f, 0.f, 0.f}, acc01 = (f4v){0.f, 0.f, 0.f, 0.f};
        f4v acc10 = (f4v){0.f, 0.f, 0.f, 0.f}, acc11 = (f4v){0.f, 0.f, 0.f, 0.f};

        // B group 0 first in FIFO (clean), then next tile's HBM loads
        s8v bq0[4], bq1[4];
        LOADB(bq0, 0);
        __builtin_amdgcn_sched_barrier(0);
        if (t < TPB - 1) {
#pragma unroll
            for (int i = 0; i < 8; ++i)
                st[i] = *reinterpret_cast<const f4v*>(fb + (size_t)(t + 1) * LT * Dsz + i * 4);
        }
        __builtin_amdgcn_sched_barrier(0);

        GROUP(0, bq0, bq1); GROUP(1, bq1, bq0);
        GROUP(2, bq0, bq1); GROUP(3, bq1, bq0);
        GROUP(4, bq0, bq1); GROUP(5, bq1, bq0);
        GROUP(6, bq0, bq1); GROUP(7, bq1, bq0);

        // ---- epilogue: per-row sum of tanh(x)*V over this wave's 32 cols ----
        {
            float rs[2][4];
#pragma unroll
            for (int r = 0; r < 4; ++r) {
                {
                    int col = w * 32 + lr;
                    float x = acc00[r] + hp[col];
                    float e = __expf(2.f * x);
                    rs[0][r] = (1.f - 2.f / (e + 1.f)) * vv[col];
                    x = acc01[r] + hp[col + 16];
                    e = __expf(2.f * x);
                    rs[0][r] = fmaf(1.f - 2.f / (e + 1.f), vv[col + 16], rs[0][r]);
                }
                {
                    int col = w * 32 + lr;
                    float x = acc10[r] + hp[col];
                    float e = __expf(2.f * x);
                    rs[1][r] = (1.f - 2.f / (e + 1.f)) * vv[col];
                    x = acc11[r] + hp[col + 16];
                    e = __expf(2.f * x);
                    rs[1][r] = fmaf(1.f - 2.f / (e + 1.f), vv[col + 16], rs[1][r]);
                }
            }
#pragma unroll
            for (int off = 1; off < 16; off <<= 1)
#pragma unroll
                for (int mf = 0; mf < 2; ++mf)
#pragma unroll
                    for (int r = 0; r < 4; ++r)
                        rs[mf][r] += __shfl_xor(rs[mf][r], off, 64);
            if (lr == 0)
#pragma unroll
                for (int mf = 0; mf < 2; ++mf)
#pragma unroll
                    for (int r = 0; r < 4; ++r)
                        spart[w][mf * 16 + lg * 4 + r] = rs[mf][r];
        }
        barrier_lds();

        // ---- scores -> exp (lanes 0..31 of wave 0) ----
        if (tid < LT) {
            float s = Vb[0];
#pragma unroll
            for (int ww = 0; ww < 8; ++ww) s += spart[ww][tid];
            float e = __expf(s);
            el[tid] = e;
            el_arr[(size_t)b * Lsz + (q8 * TPB + t) * LT + tid] = e;
            dsum += e;
        }
        barrier_lds();

        // ---- ctx accumulate (persistent regs) from swizzled LDS tile ----
#pragma unroll
        for (int li = 0; li < 16; ++li) {
            int l = half * 16 + li;
            unsigned int pk = *reinterpret_cast<const unsigned int*>(&A[l][SW(l, d0)]);
            float e = el[l];
            cacc0 = fmaf(e, bf2f(pk & 0xFFFFu), cacc0);
            cacc1 = fmaf(e, bf2f(pk >> 16), cacc1);
        }
        barrier_lds();

        // ---- write staged tile t+1 (loads issued ~5000cy ago: no stall) ----
        if (t < TPB - 1) {
#pragma unroll
            for (int j = 0; j < 4; ++j) {
                u16x8 o = { f2bf(st[2 * j].x),     f2bf(st[2 * j].y),
                            f2bf(st[2 * j].z),     f2bf(st[2 * j].w),
                            f2bf(st[2 * j + 1].x), f2bf(st[2 * j + 1].y),
                            f2bf(st[2 * j + 1].z), f2bf(st[2 * j + 1].w) };
                *reinterpret_cast<u16x8*>(&A[srow][SW(srow, sfc + j * 8)]) = o;
            }
            barrier_lds();
        }
    }

    // ---- final reductions: den + ctx (one atomic each) ----
    if (tid < LT) {
#pragma unroll
        for (int off = 1; off < 32; off <<= 1) dsum += __shfl_xor(dsum, off, 64);
        if (tid == 0) atomicAdd(&den[b], dsum);
    }
    pc[half][d0]     = cacc0;
    pc[half][d0 + 1] = cacc1;
    barrier_lds();
    atomicAdd(&ctx_acc[b * Dsz + tid], pc[0][tid] + pc[1][tid]);
}

__global__ __launch_bounds__(256) void k_finalize(const float* __restrict__ el_arr,
                                                  const float* __restrict__ den,
                                                  const float* __restrict__ ctx_acc,
                                                  float* __restrict__ ctx,
                                                  float* __restrict__ wout) {
    int blk = blockIdx.x, tid = threadIdx.x;
    int b = blk >> 2, q = blk & 3;
    float inv = 1.f / den[b];
    size_t base = (size_t)b * Lsz + q * 1024 + tid * 4;
    f4v e4 = *reinterpret_cast<const f4v*>(&el_arr[base]);
    f4v w4 = { e4.x * inv, e4.y * inv, e4.z * inv, e4.w * inv };
    *reinterpret_cast<f4v*>(&wout[base]) = w4;
    if (tid < 128) {
        int d = q * 128 + tid;
        ctx[(size_t)b * Dsz + d] = ctx_acc[b * Dsz + d] * inv;
    }
}

extern "C" void kernel_launch(void* const* d_in, const int* in_sizes, int n_in,
                              void* d_out, int out_size, void* d_ws, size_t ws_size,
                              hipStream_t stream) {
    const float* feat   = (const float*)d_in[0];
    const float* hidden = (const float*)d_in[1];
    const float* W1     = (const float*)d_in[2];
    const float* W1b    = (const float*)d_in[3];
    const float* W2     = (const float*)d_in[4];
    const float* W2b    = (const float*)d_in[5];
    const float* Vk     = (const float*)d_in[6];
    const float* Vb     = (const float*)d_in[7];

    unsigned short* w1t = (unsigned short*)d_ws;
    float* hp_part = (float*)((char*)d_ws + 256 * 1024);
    float* el_arr  = (float*)((char*)d_ws + 512 * 1024);
    float* den     = (float*)((char*)d_ws + 1536 * 1024);
    float* ctx_acc = (float*)((char*)d_ws + 1536 * 1024 + 256);

    float* ctx  = (float*)d_out;              // [64, 512]
    float* wout = ctx + Bsz * Dsz;            // [64, 4096, 1]

    k_prep<<<352, 256, 0, stream>>>(W1, hidden, W2, w1t, hp_part, den, ctx_acc);
    k_score_ctx<<<Bsz * NQB, 512, 0, stream>>>(feat, w1t, hp_part, W1b, W2b,
                                               Vk, Vb, el_arr, den, ctx_acc);
    k_finalize<<<Bsz * 4, 256, 0, stream>>>(el_arr, den, ctx_acc, ctx, wout);
}

// Round 14
// 319.582 us; speedup vs baseline: 1.2820x; 1.2820x over previous
//
#include <hip/hip_runtime.h>

#define Bsz 64
#define Lsz 4096
#define Dsz 512
#define Hsz 512
#define Usz 256
#define LT  32
#define NLB (Lsz / LT)          // 128 tiles/batch -> 8192 blocks

typedef __attribute__((ext_vector_type(8))) short s8v;     // bf16x8 MFMA frag
typedef __attribute__((ext_vector_type(4))) float f4v;
typedef __attribute__((ext_vector_type(2))) float f2v;
typedef __attribute__((ext_vector_type(8))) unsigned short u16x8;

// XOR swizzle: 16B slot (8 shorts) ^= row&7; bijective on [32][512] tile
#define SW(r, c) (((((c) >> 3) ^ ((r) & 7)) << 3) | ((c) & 7))

__device__ __forceinline__ unsigned short f2bf(float f) {
    unsigned int u = __float_as_uint(f);
    u += 0x7FFFu + ((u >> 16) & 1u);   // RNE
    return (unsigned short)(u >> 16);
}
__device__ __forceinline__ float bf2f(unsigned int lo16) {
    return __uint_as_float(lo16 << 16);
}

// ws layout
//   [0,     256K)      : W1T bf16 [256][512]
//   [256K,  512K)      : hp_part f32 [4][64][256]
//   [512K, 1536K)      : el_arr f32 [64][4096]
//   [1536K, +256B)     : den f32 [64]
//   [1536K+256, +128K) : ctx_acc f32 [64][512]

__global__ __launch_bounds__(256) void k_prep(const float* __restrict__ W1,
                                              const float* __restrict__ hidden,
                                              const float* __restrict__ W2,
                                              unsigned short* __restrict__ W1T,
                                              float* __restrict__ hp_part,
                                              float* __restrict__ den,
                                              float* __restrict__ ctx_acc) {
    int blk = blockIdx.x, tid = threadIdx.x;
    if (blk < 32) {
        __shared__ unsigned short Lt[64][72];
        int kb = blk >> 2, ub = blk & 3;
        {
            int rr = tid >> 2, c16 = (tid & 3) * 16;
            const float* src = W1 + (size_t)(kb * 64 + rr) * Usz + ub * 64 + c16;
            f4v v0 = *reinterpret_cast<const f4v*>(src);
            f4v v1 = *reinterpret_cast<const f4v*>(src + 4);
            f4v v2 = *reinterpret_cast<const f4v*>(src + 8);
            f4v v3 = *reinterpret_cast<const f4v*>(src + 12);
            u16x8 o0 = { f2bf(v0.x), f2bf(v0.y), f2bf(v0.z), f2bf(v0.w),
                         f2bf(v1.x), f2bf(v1.y), f2bf(v1.z), f2bf(v1.w) };
            u16x8 o1 = { f2bf(v2.x), f2bf(v2.y), f2bf(v2.z), f2bf(v2.w),
                         f2bf(v3.x), f2bf(v3.y), f2bf(v3.z), f2bf(v3.w) };
            *reinterpret_cast<u16x8*>(&Lt[rr][c16])     = o0;
            *reinterpret_cast<u16x8*>(&Lt[rr][c16 + 8]) = o1;
        }
        __syncthreads();
        {
            int ur = tid >> 2, k16 = (tid & 3) * 16;
            u16x8 o0, o1;
#pragma unroll
            for (int i = 0; i < 8; ++i) o0[i] = Lt[k16 + i][ur];
#pragma unroll
            for (int i = 0; i < 8; ++i) o1[i] = Lt[k16 + 8 + i][ur];
            unsigned short* dst = W1T + (size_t)(ub * 64 + ur) * Dsz + kb * 64 + k16;
            *reinterpret_cast<u16x8*>(dst)     = o0;
            *reinterpret_cast<u16x8*>(dst + 8) = o1;
        }
    } else if (blk < 288) {
        int idx = blk - 32;
        int kq = idx >> 6, b = idx & 63;
        const float* hrow = hidden + (size_t)b * Hsz + kq * 128;
        const float* w2p  = W2 + (size_t)(kq * 128) * Usz + tid;
        float a0 = 0.f, a1 = 0.f, a2 = 0.f, a3 = 0.f;
#pragma unroll 8
        for (int k = 0; k < 128; k += 4) {
            a0 = fmaf(hrow[k + 0], w2p[(size_t)(k + 0) * Usz], a0);
            a1 = fmaf(hrow[k + 1], w2p[(size_t)(k + 1) * Usz], a1);
            a2 = fmaf(hrow[k + 2], w2p[(size_t)(k + 2) * Usz], a2);
            a3 = fmaf(hrow[k + 3], w2p[(size_t)(k + 3) * Usz], a3);
        }
        hp_part[((size_t)kq * Bsz + b) * Usz + tid] = (a0 + a1) + (a2 + a3);
    } else {
        int b = blk - 288;
        if (tid == 0) den[b] = 0.f;
        ctx_acc[b * Dsz + tid] = 0.f;
        ctx_acc[b * Dsz + 256 + tid] = 0.f;
    }
}

#define LOADB(dst, ks)                                                         \
    {                                                                          \
        dst[0] = *reinterpret_cast<const s8v*>(bp0 + (ks) * 32);               \
        dst[1] = *reinterpret_cast<const s8v*>(bp0 + 8192  + (ks) * 32);       \
        dst[2] = *reinterpret_cast<const s8v*>(bp0 + 16384 + (ks) * 32);       \
        dst[3] = *reinterpret_cast<const s8v*>(bp0 + 24576 + (ks) * 32);       \
    }

#define GEMM1(ks, cur)                                                         \
    {                                                                          \
        const int kof = (ks) * 32 + lg * 8;                                    \
        s8v a0 = *reinterpret_cast<const s8v*>(&A[lr][SW(lr, kof)]);           \
        s8v a1 = *reinterpret_cast<const s8v*>(&A[16 + lr][SW(16 + lr, kof)]); \
        acc[0][0] = __builtin_amdgcn_mfma_f32_16x16x32_bf16(a0, cur[0], acc[0][0], 0, 0, 0); \
        acc[0][1] = __builtin_amdgcn_mfma_f32_16x16x32_bf16(a0, cur[1], acc[0][1], 0, 0, 0); \
        acc[0][2] = __builtin_amdgcn_mfma_f32_16x16x32_bf16(a0, cur[2], acc[0][2], 0, 0, 0); \
        acc[0][3] = __builtin_amdgcn_mfma_f32_16x16x32_bf16(a0, cur[3], acc[0][3], 0, 0, 0); \
        acc[1][0] = __builtin_amdgcn_mfma_f32_16x16x32_bf16(a1, cur[0], acc[1][0], 0, 0, 0); \
        acc[1][1] = __builtin_amdgcn_mfma_f32_16x16x32_bf16(a1, cur[1], acc[1][1], 0, 0, 0); \
        acc[1][2] = __builtin_amdgcn_mfma_f32_16x16x32_bf16(a1, cur[2], acc[1][2], 0, 0, 0); \
        acc[1][3] = __builtin_amdgcn_mfma_f32_16x16x32_bf16(a1, cur[3], acc[1][3], 0, 0, 0); \
    }

#define GROUP(ks, cur, nxt)                                                    \
    {                                                                          \
        if ((ks) < 15) LOADB(nxt, (ks) + 1);                                   \
        __builtin_amdgcn_sched_barrier(0);                                     \
        GEMM1(ks, cur);                                                        \
    }

// 8192 blocks x 256 thr (4 waves, 64 U-cols each). LDS ~35KB -> 4 blocks/CU
// (16 waves/CU). Halved LDS-read amplification (4 waves read the tile, not 8)
// + depth-2 B ring for per-wave ILP. arch live ~50 regs -> no spill at 64.
__global__ __launch_bounds__(256, 4) void k_score_ctx(
    const float* __restrict__ feat, const unsigned short* __restrict__ W1T,
    const float* __restrict__ hp_part, const float* __restrict__ W1b,
    const float* __restrict__ W2b, const float* __restrict__ Vk,
    const float* __restrict__ Vb, float* __restrict__ el_arr,
    float* __restrict__ den, float* __restrict__ ctx_acc)
{
    __shared__ __align__(16) unsigned short A[LT][Dsz];  // 32 KiB, swizzled
    __shared__ float hp[Usz], vv[Usz];
    __shared__ float spart[4][LT];
    __shared__ float el[LT];

    const int tid  = threadIdx.x;
    const int w    = tid >> 6;
    const int lane = tid & 63;
    const int lr   = lane & 15;
    const int lg   = lane >> 4;
    const int b    = blockIdx.x >> 7;
    const int lb   = blockIdx.x & 127;
    const int l0   = lb * LT;

    {   // 256 threads == Usz: every thread loads one hp/vv entry
        const float* hpb = hp_part + (size_t)b * Usz + tid;
        hp[tid] = (hpb[0] + hpb[Bsz * Usz]) + (hpb[2 * Bsz * Usz] + hpb[3 * Bsz * Usz])
                + W1b[tid] + W2b[tid];
        vv[tid] = Vk[tid];
    }

    // ---- stage 32x512 fp32 -> bf16 swizzled (4 batches of 4 f4v = 16 regs) ----
    {
        const int row = tid >> 3;                 // 0..31
        const int cb  = (tid & 7) * 16;           // float col within 128-chunk
        const float* fp = feat + ((size_t)b * Lsz + l0 + row) * Dsz + cb;
#pragma unroll
        for (int j = 0; j < 4; ++j) {
            f4v s0 = *reinterpret_cast<const f4v*>(fp + j * 128);
            f4v s1 = *reinterpret_cast<const f4v*>(fp + j * 128 + 4);
            f4v s2 = *reinterpret_cast<const f4v*>(fp + j * 128 + 8);
            f4v s3 = *reinterpret_cast<const f4v*>(fp + j * 128 + 12);
            u16x8 o = { f2bf(s0.x), f2bf(s0.y), f2bf(s0.z), f2bf(s0.w),
                        f2bf(s1.x), f2bf(s1.y), f2bf(s1.z), f2bf(s1.w) };
            u16x8 p = { f2bf(s2.x), f2bf(s2.y), f2bf(s2.z), f2bf(s2.w),
                        f2bf(s3.x), f2bf(s3.y), f2bf(s3.z), f2bf(s3.w) };
            const int sc = j * 128 + cb;
            *reinterpret_cast<u16x8*>(&A[row][SW(row, sc)])     = o;
            *reinterpret_cast<u16x8*>(&A[row][SW(row, sc + 8)]) = p;
        }
    }
    __syncthreads();

    // ---- GEMM: 32 rows x this wave's 64 U-cols x K=512, depth-2 B ring ----
    const unsigned short* bp0 = W1T + (size_t)(w * 64 + lr) * Dsz + lg * 8;
    f4v acc[2][4];
#pragma unroll
    for (int mf = 0; mf < 2; ++mf)
#pragma unroll
        for (int nf = 0; nf < 4; ++nf) acc[mf][nf] = (f4v){0.f, 0.f, 0.f, 0.f};

    {
        s8v ba[4], bb[4];
        LOADB(ba, 0);
        GROUP(0,  ba, bb); GROUP(1,  bb, ba); GROUP(2,  ba, bb); GROUP(3,  bb, ba);
        GROUP(4,  ba, bb); GROUP(5,  bb, ba); GROUP(6,  ba, bb); GROUP(7,  bb, ba);
        GROUP(8,  ba, bb); GROUP(9,  bb, ba); GROUP(10, ba, bb); GROUP(11, bb, ba);
        GROUP(12, ba, bb); GROUP(13, bb, ba); GROUP(14, ba, bb); GROUP(15, bb, ba);
    }

    // ---- epilogue: per-row sum of tanh(x)*V over this wave's 64 cols ----
    {
        float rs[2][4];
#pragma unroll
        for (int mf = 0; mf < 2; ++mf)
#pragma unroll
            for (int r = 0; r < 4; ++r) rs[mf][r] = 0.f;
#pragma unroll
        for (int mf = 0; mf < 2; ++mf)
#pragma unroll
            for (int nf = 0; nf < 4; ++nf) {
                int col = w * 64 + nf * 16 + lr;
                float hpv = hp[col], vvv = vv[col];
#pragma unroll
                for (int r = 0; r < 4; ++r) {
                    float x = acc[mf][nf][r] + hpv;
                    float e = __expf(2.f * x);
                    rs[mf][r] = fmaf(1.f - 2.f / (e + 1.f), vvv, rs[mf][r]);
                }
            }
#pragma unroll
        for (int off = 1; off < 16; off <<= 1)
#pragma unroll
            for (int mf = 0; mf < 2; ++mf)
#pragma unroll
                for (int r = 0; r < 4; ++r)
                    rs[mf][r] += __shfl_xor(rs[mf][r], off, 64);
        if (lr == 0)
#pragma unroll
            for (int mf = 0; mf < 2; ++mf)
#pragma unroll
                for (int r = 0; r < 4; ++r)
                    spart[w][mf * 16 + lg * 4 + r] = rs[mf][r];
    }
    __syncthreads();

    // ---- scores -> exp -> denominator partial (lanes 0..31) ----
    if (tid < LT) {
        float s = Vb[0] + (spart[0][tid] + spart[1][tid]) + (spart[2][tid] + spart[3][tid]);
        float e = __expf(s);
        el[tid] = e;
        el_arr[(size_t)b * Lsz + l0 + tid] = e;
        float es = e;
#pragma unroll
        for (int off = 1; off < 32; off <<= 1) es += __shfl_xor(es, off, 64);
        if (tid == 0) atomicAdd(&den[b], es);
    }
    __syncthreads();

    // ---- context: thread owns d={2t,2t+1}; u32 swizzled reads, 2-way free ----
    {
        const int d0 = tid * 2;
        float c0 = 0.f, c1 = 0.f;
#pragma unroll 8
        for (int l = 0; l < LT; ++l) {
            unsigned int pk = *reinterpret_cast<const unsigned int*>(&A[l][SW(l, d0)]);
            float e = el[l];
            c0 = fmaf(e, bf2f(pk & 0xFFFFu), c0);
            c1 = fmaf(e, bf2f(pk >> 16), c1);
        }
        atomicAdd(&ctx_acc[b * Dsz + d0],     c0);
        atomicAdd(&ctx_acc[b * Dsz + d0 + 1], c1);
    }
}

__global__ __launch_bounds__(256) void k_finalize(const float* __restrict__ el_arr,
                                                  const float* __restrict__ den,
                                                  const float* __restrict__ ctx_acc,
                                                  float* __restrict__ ctx,
                                                  float* __restrict__ wout) {
    int blk = blockIdx.x, tid = threadIdx.x;
    int b = blk >> 2, q = blk & 3;
    float inv = 1.f / den[b];
    size_t base = (size_t)b * Lsz + q * 1024 + tid * 4;
    f4v e4 = *reinterpret_cast<const f4v*>(&el_arr[base]);
    f4v w4 = { e4.x * inv, e4.y * inv, e4.z * inv, e4.w * inv };
    *reinterpret_cast<f4v*>(&wout[base]) = w4;
    if (tid < 128) {
        int d = q * 128 + tid;
        ctx[(size_t)b * Dsz + d] = ctx_acc[b * Dsz + d] * inv;
    }
}

extern "C" void kernel_launch(void* const* d_in, const int* in_sizes, int n_in,
                              void* d_out, int out_size, void* d_ws, size_t ws_size,
                              hipStream_t stream) {
    const float* feat   = (const float*)d_in[0];
    const float* hidden = (const float*)d_in[1];
    const float* W1     = (const float*)d_in[2];
    const float* W1b    = (const float*)d_in[3];
    const float* W2     = (const float*)d_in[4];
    const float* W2b    = (const float*)d_in[5];
    const float* Vk     = (const float*)d_in[6];
    const float* Vb     = (const float*)d_in[7];

    unsigned short* w1t = (unsigned short*)d_ws;
    float* hp_part = (float*)((char*)d_ws + 256 * 1024);
    float* el_arr  = (float*)((char*)d_ws + 512 * 1024);
    float* den     = (float*)((char*)d_ws + 1536 * 1024);
    float* ctx_acc = (float*)((char*)d_ws + 1536 * 1024 + 256);

    float* ctx  = (float*)d_out;              // [64, 512]
    float* wout = ctx + Bsz * Dsz;            // [64, 4096, 1]

    k_prep<<<352, 256, 0, stream>>>(W1, hidden, W2, w1t, hp_part, den, ctx_acc);
    k_score_ctx<<<Bsz * NLB, 256, 0, stream>>>(feat, w1t, hp_part, W1b, W2b,
                                               Vk, Vb, el_arr, den, ctx_acc);
    k_finalize<<<Bsz * 4, 256, 0, stream>>>(el_arr, den, ctx_acc, ctx, wout);
}